// Round 13
// baseline (165.854 us; speedup 1.0000x reference)
//
#include <hip/hip_runtime.h>
#include <stdint.h>

typedef _Float16 hf8  __attribute__((ext_vector_type(8)));
typedef float  f32x16 __attribute__((ext_vector_type(16)));

constexpr int Bn = 512;
constexpr int Nn = 1024;
constexpr int Pn = 2016;
constexpr int H1c = 128;
constexpr int H2c = 64;
constexpr int NCc = 40;
constexpr int NT  = 512;    // threads per block (8 waves)
constexpr int NW  = 8;
constexpr int TS  = 136;    // T2 row stride in f16 units (272 B padded-linear, R12-proven)
constexpr int TBYTES = 73728;  // staged bytes per batch: 9 rounds x 512 lanes x 16 B (>= 256*272)

__device__ __forceinline__ void gload_lds16(const void* g, void* l) {
    __builtin_amdgcn_global_load_lds(
        reinterpret_cast<const uint32_t __attribute__((address_space(1)))*>(
            reinterpret_cast<uintptr_t>(g)),
        reinterpret_cast<uint32_t __attribute__((address_space(3)))*>(
            reinterpret_cast<uintptr_t>(l)),
        16, 0, 0);
}

// Pre-pack W2 (128x64 f32) + b2 into f16 A-fragments for mfma_f32_32x32x16_f16
// (R8-R12-proven operand geometry), hi-only.
__global__ void prep_w2(const float* __restrict__ W2, const float* __restrict__ b2,
                        _Float16* __restrict__ hi) {
    int i = blockIdx.x * 256 + threadIdx.x;
    if (i >= 9216) return;
    int jj = i & 7, colm = (i >> 3) & 31, kh = (i >> 8) & 1, nt = (i >> 9) & 1, c = i >> 10;
    int j = nt * 32 + colm;
    float v;
    if (c < 8) { int k = c * 16 + kh * 8 + jj; v = W2[k * H2c + j]; }
    else       { v = (kh == 0 && jj == 0) ? b2[j] : 0.f; }
    hi[i] = (_Float16)v;
}

// Materialize the padded T2 image per batch into global scratch:
// byte b*73728 + gp*272 + h*2 holds f16 of
//   sum_c pts[k1][c]*W1[(6g+c)*128+h] + pts[k2][c]*W1[(6g+3+c)*128+h]  (+b1[h] if g==0)
// with gp = g*64 + k1*8 + k2. Each thread writes one h-PAIR (u32).
__global__ void prep_t2(const float* __restrict__ x, const int* __restrict__ idx,
                        const float* __restrict__ W1, const float* __restrict__ b1,
                        _Float16* __restrict__ T2g) {
    int i = blockIdx.x * 256 + threadIdx.x;    // 512*256*64 = 8,388,608 pairs
    int e  = i & 63;
    int gp = (i >> 6) & 255;
    int b  = i >> 14;
    int g = gp >> 6, p = gp & 63, k1 = p >> 3, k2 = p & 7;
    const float* xb = x + (size_t)b * (Nn * 3);
    const int i1 = idx[k1], i2 = idx[k2];
    float p10 = xb[i1 * 3 + 0], p11 = xb[i1 * 3 + 1], p12 = xb[i1 * 3 + 2];
    float p20 = xb[i2 * 3 + 0], p21 = xb[i2 * 3 + 1], p22 = xb[i2 * 3 + 2];
    const float* w = W1 + 6 * g * H1c;
    int h0 = 2 * e, h1 = 2 * e + 1;
    float v0 = p10 * w[h0] + p11 * w[H1c + h0] + p12 * w[2 * H1c + h0]
             + p20 * w[3 * H1c + h0] + p21 * w[4 * H1c + h0] + p22 * w[5 * H1c + h0];
    float v1 = p10 * w[h1] + p11 * w[H1c + h1] + p12 * w[2 * H1c + h1]
             + p20 * w[3 * H1c + h1] + p21 * w[4 * H1c + h1] + p22 * w[5 * H1c + h1];
    if (g == 0) { v0 += b1[h0]; v1 += b1[h1]; }
    unsigned short u0 = __builtin_bit_cast(unsigned short, (_Float16)v0);
    unsigned short u1 = __builtin_bit_cast(unsigned short, (_Float16)v1);
    *(unsigned int*)((char*)T2g + (size_t)b * TBYTES + gp * 272 + (e << 2)) =
        (unsigned int)u0 | ((unsigned int)u1 << 16);
}

// ---------------- main kernel, STAGED variant ----------------
__global__ __launch_bounds__(NT, 4)
void mlp_staged(const int* __restrict__ perms,
                const float* __restrict__ W3, const float* __restrict__ b3,
                const _Float16* __restrict__ w2hi,
                const _Float16* __restrict__ T2g,
                float* __restrict__ out)
{
    __shared__ _Float16 T2h[TBYTES / 2];   // 73728 B, padded-linear (gp*136 + h)
    __shared__ float wred[NW][64];
    __shared__ float Hs[64];

    const int t = threadIdx.x, b = blockIdx.x;
    const int lane = t & 63, wave = t >> 6;

    // ---- stage T2 image: 9 x (512 lanes x 16 B) = 73728 B, linear->linear ----
    {
        const char* gs = (const char*)T2g + (size_t)b * TBYTES + wave * 1024 + lane * 16;
        char* ls = (char*)T2h + wave * 1024;
        #pragma unroll
        for (int r = 0; r < 9; ++r)
            gload_lds16(gs + r * 8192, ls + r * 8192);
    }
    __syncthreads();   // drains vmcnt before any ds_read

    const int kh = lane >> 5, colm = lane & 31;
    const char* Tb = (const char*)T2h;

    float vsum[32];
    #pragma unroll
    for (int q = 0; q < 32; ++q) vsum[q] = 0.f;

    const _Float16* w2L = w2hi + (kh * 32 + colm) * 8;
    const hf8 bias0 = *(const hf8*)(w2L + 8 * 1024);
    const hf8 bias1 = *(const hf8*)(w2L + 8 * 1024 + 512);
    hf8 Bone = {};
    if (kh == 0) Bone[0] = (_Float16)1.0f;

    #pragma unroll 1
    for (int tile = wave; tile < 63; tile += NW) {
        const int4* pp = (const int4*)(perms + ((size_t)b * Pn + (tile << 5) + colm) * 8);
        int4 pa = pp[0];
        int4 pb = pp[1];
        const int gp0 = pa.x * 8 + pa.y;
        const int gp1 = 64  + pa.z * 8 + pa.w;
        const int gp2 = 128 + pb.x * 8 + pb.y;
        const int gp3 = 192 + pb.z * 8 + pb.w;
        const int khb = kh << 4;
        const int ba0 = gp0 * 272 + khb;
        const int ba1 = gp1 * 272 + khb;
        const int ba2 = gp2 * 272 + khb;
        const int ba3 = gp3 * 272 + khb;

        f32x16 acc0, acc1;
        #pragma unroll
        for (int q = 0; q < 16; ++q) { acc0[q] = 0.f; acc1[q] = 0.f; }

        #pragma unroll 2
        for (int c = 0; c < 8; ++c) {
            const int co = c << 5;
            hf8 r0 = *(const hf8*)(Tb + ba0 + co);
            hf8 r1 = *(const hf8*)(Tb + ba1 + co);
            hf8 r2 = *(const hf8*)(Tb + ba2 + co);
            hf8 r3 = *(const hf8*)(Tb + ba3 + co);
            hf8 s = (r0 + r1) + (r2 + r3);
            hf8 z = {};
            s = __builtin_elementwise_max(s, z);

            hf8 Ah0 = *(const hf8*)(w2L + c * 1024);
            hf8 Ah1 = *(const hf8*)(w2L + c * 1024 + 512);
            acc0 = __builtin_amdgcn_mfma_f32_32x32x16_f16(Ah0, s, acc0, 0, 0, 0);
            acc1 = __builtin_amdgcn_mfma_f32_32x32x16_f16(Ah1, s, acc1, 0, 0, 0);
        }

        acc0 = __builtin_amdgcn_mfma_f32_32x32x16_f16(bias0, Bone, acc0, 0, 0, 0);
        acc1 = __builtin_amdgcn_mfma_f32_32x32x16_f16(bias1, Bone, acc1, 0, 0, 0);

        #pragma unroll
        for (int r = 0; r < 16; ++r) vsum[r]      += fmaxf(acc0[r], 0.f);
        #pragma unroll
        for (int r = 0; r < 16; ++r) vsum[16 + r] += fmaxf(acc1[r], 0.f);
    }

    #pragma unroll
    for (int nt = 0; nt < 2; ++nt) {
        #pragma unroll
        for (int r = 0; r < 16; ++r) {
            int j = nt * 32 + (r & 3) + 8 * (r >> 2) + 4 * kh;
            float v = vsum[nt * 16 + r];
            v += __shfl_xor(v, 1);
            v += __shfl_xor(v, 2);
            v += __shfl_xor(v, 4);
            v += __shfl_xor(v, 8);
            v += __shfl_xor(v, 16);
            if (colm == 0) wred[wave][j] = v;
        }
    }
    __syncthreads();

    if (t < 64) {
        float s2 = 0.f;
        #pragma unroll
        for (int w = 0; w < NW; ++w) s2 += wred[w][t];
        Hs[t] = s2;
    }
    __syncthreads();

    if (t < NCc) {
        constexpr float invP = 1.f / (float)Pn;
        float s3 = 0.f;
        #pragma unroll
        for (int j = 0; j < 64; ++j) s3 = fmaf(W3[j * NCc + t], Hs[j], s3);
        out[b * NCc + t] = b3[t] + s3 * invP;
    }
}

// ---------------- fallback: R12 kernel (in-LDS build), verbatim ----------------
__global__ __launch_bounds__(NT, 4)
void mlp_build(const float* __restrict__ x, const int* __restrict__ idx,
               const int* __restrict__ perms,
               const float* __restrict__ W1, const float* __restrict__ b1,
               const float* __restrict__ W3, const float* __restrict__ b3,
               const _Float16* __restrict__ w2hi,
               float* __restrict__ out)
{
    __shared__ _Float16 T2h[256 * TS];
    __shared__ float ptsl[24];
    __shared__ float wred[NW][64];
    __shared__ float Hs[64];

    const int t = threadIdx.x, b = blockIdx.x;

    if (t < 24) {
        int k = t / 3, c = t % 3;
        ptsl[t] = x[((size_t)b * Nn + idx[k]) * 3 + c];
    }
    __syncthreads();

    #pragma unroll 2
    for (int i = 0; i < 64; ++i) {
        int e = t + (i << 9);
        int h = e & 127, gp = e >> 7;
        int g = gp >> 6, p = gp & 63, k1 = p >> 3, k2 = p & 7;
        float v = ptsl[k1 * 3 + 0] * W1[(6 * g + 0) * H1c + h]
                + ptsl[k1 * 3 + 1] * W1[(6 * g + 1) * H1c + h]
                + ptsl[k1 * 3 + 2] * W1[(6 * g + 2) * H1c + h]
                + ptsl[k2 * 3 + 0] * W1[(6 * g + 3) * H1c + h]
                + ptsl[k2 * 3 + 1] * W1[(6 * g + 4) * H1c + h]
                + ptsl[k2 * 3 + 2] * W1[(6 * g + 5) * H1c + h];
        if (g == 0) v += b1[h];
        T2h[gp * TS + h] = (_Float16)v;
    }
    __syncthreads();

    const int lane = t & 63, wave = t >> 6;
    const int kh = lane >> 5, colm = lane & 31;
    const char* Tb = (const char*)T2h;

    float vsum[32];
    #pragma unroll
    for (int q = 0; q < 32; ++q) vsum[q] = 0.f;

    const _Float16* w2L = w2hi + (kh * 32 + colm) * 8;
    const hf8 bias0 = *(const hf8*)(w2L + 8 * 1024);
    const hf8 bias1 = *(const hf8*)(w2L + 8 * 1024 + 512);
    hf8 Bone = {};
    if (kh == 0) Bone[0] = (_Float16)1.0f;

    #pragma unroll 1
    for (int tile = wave; tile < 63; tile += NW) {
        const int4* pp = (const int4*)(perms + ((size_t)b * Pn + (tile << 5) + colm) * 8);
        int4 pa = pp[0];
        int4 pb = pp[1];
        const int gp0 = pa.x * 8 + pa.y;
        const int gp1 = 64  + pa.z * 8 + pa.w;
        const int gp2 = 128 + pb.x * 8 + pb.y;
        const int gp3 = 192 + pb.z * 8 + pb.w;
        const int khb = kh << 4;
        const int ba0 = gp0 * 272 + khb;
        const int ba1 = gp1 * 272 + khb;
        const int ba2 = gp2 * 272 + khb;
        const int ba3 = gp3 * 272 + khb;

        f32x16 acc0, acc1;
        #pragma unroll
        for (int q = 0; q < 16; ++q) { acc0[q] = 0.f; acc1[q] = 0.f; }

        #pragma unroll 2
        for (int c = 0; c < 8; ++c) {
            const int co = c << 5;
            hf8 r0 = *(const hf8*)(Tb + ba0 + co);
            hf8 r1 = *(const hf8*)(Tb + ba1 + co);
            hf8 r2 = *(const hf8*)(Tb + ba2 + co);
            hf8 r3 = *(const hf8*)(Tb + ba3 + co);
            hf8 s = (r0 + r1) + (r2 + r3);
            hf8 z = {};
            s = __builtin_elementwise_max(s, z);

            hf8 Ah0 = *(const hf8*)(w2L + c * 1024);
            hf8 Ah1 = *(const hf8*)(w2L + c * 1024 + 512);
            acc0 = __builtin_amdgcn_mfma_f32_32x32x16_f16(Ah0, s, acc0, 0, 0, 0);
            acc1 = __builtin_amdgcn_mfma_f32_32x32x16_f16(Ah1, s, acc1, 0, 0, 0);
        }

        acc0 = __builtin_amdgcn_mfma_f32_32x32x16_f16(bias0, Bone, acc0, 0, 0, 0);
        acc1 = __builtin_amdgcn_mfma_f32_32x32x16_f16(bias1, Bone, acc1, 0, 0, 0);

        #pragma unroll
        for (int r = 0; r < 16; ++r) vsum[r]      += fmaxf(acc0[r], 0.f);
        #pragma unroll
        for (int r = 0; r < 16; ++r) vsum[16 + r] += fmaxf(acc1[r], 0.f);
    }

    #pragma unroll
    for (int nt = 0; nt < 2; ++nt) {
        #pragma unroll
        for (int r = 0; r < 16; ++r) {
            int j = nt * 32 + (r & 3) + 8 * (r >> 2) + 4 * kh;
            float v = vsum[nt * 16 + r];
            v += __shfl_xor(v, 1);
            v += __shfl_xor(v, 2);
            v += __shfl_xor(v, 4);
            v += __shfl_xor(v, 8);
            v += __shfl_xor(v, 16);
            if (colm == 0) wred[wave][j] = v;
        }
    }
    __syncthreads();

    if (t < 64) {
        float s2 = 0.f;
        #pragma unroll
        for (int w = 0; w < NW; ++w) s2 += wred[w][t];
        Hs[t] = s2;
    }
    __syncthreads();

    if (t < NCc) {
        constexpr float invP = 1.f / (float)Pn;
        float s3 = 0.f;
        #pragma unroll
        for (int j = 0; j < 64; ++j) s3 = fmaf(W3[j * NCc + t], Hs[j], s3);
        out[b * NCc + t] = b3[t] + s3 * invP;
    }
}

extern "C" void kernel_launch(void* const* d_in, const int* in_sizes, int n_in,
                              void* d_out, int out_size, void* d_ws, size_t ws_size,
                              hipStream_t stream) {
    const float* x     = (const float*)d_in[0];
    const int*   idx   = (const int*)  d_in[1];
    const int*   perms = (const int*)  d_in[2];
    const float* W1    = (const float*)d_in[3];
    const float* b1    = (const float*)d_in[4];
    const float* W2    = (const float*)d_in[5];
    const float* b2    = (const float*)d_in[6];
    const float* W3    = (const float*)d_in[7];
    const float* b3    = (const float*)d_in[8];
    float* out = (float*)d_out;

    _Float16* wsHi = (_Float16*)d_ws;                       // 9216 f16 = 18432 B
    _Float16* T2g  = (_Float16*)((char*)d_ws + 32768);      // 512 * 73728 B

    const size_t need = 32768 + (size_t)Bn * TBYTES;

    hipLaunchKernelGGL(prep_w2, dim3(36), dim3(256), 0, stream, W2, b2, wsHi);
    if (ws_size >= need) {
        hipLaunchKernelGGL(prep_t2, dim3(32768), dim3(256), 0, stream, x, idx, W1, b1, T2g);
        hipLaunchKernelGGL(mlp_staged, dim3(Bn), dim3(NT), 0, stream,
                           perms, W3, b3, wsHi, T2g, out);
    } else {
        hipLaunchKernelGGL(mlp_build, dim3(Bn), dim3(NT), 0, stream,
                           x, idx, perms, W1, b1, W3, b3, wsHi, out);
    }
}